// Round 16
// baseline (423.005 us; speedup 1.0000x reference)
//
#include <hip/hip_runtime.h>
#include <math.h>

#define NN 10000
#define NE 160000
#define NB 128
#define NH 4
#define DOUT 512
#define NEG 0.2f
#define SCAN_BLKS ((NN + 255) / 256)   // 40
#define CNT_BLKS ((NE + 255) / 256)    // 625

typedef __attribute__((ext_vector_type(8))) short short8;
typedef __attribute__((ext_vector_type(4))) float f32x4;
typedef __attribute__((ext_vector_type(4))) unsigned short us4;

__device__ __forceinline__ float leakyf(float v){ return v > 0.f ? v : NEG*v; }
__device__ __forceinline__ void fma4(float4& a, const float4 v, float w){
  a.x += v.x*w; a.y += v.y*w; a.z += v.z*w; a.w += v.w*w;
}
__device__ __forceinline__ void mul4(float4& a, float s){
  a.x *= s; a.y *= s; a.z *= s; a.w *= s;
}
__device__ __forceinline__ unsigned short f2bf(float f){
  unsigned int u = __float_as_uint(f);
  u += 0x7FFFu + ((u >> 16) & 1u);
  return (unsigned short)(u >> 16);
}
__device__ __forceinline__ float bf2f(unsigned short h){
  return __uint_as_float(((unsigned int)h) << 16);
}
__device__ __forceinline__ void split2(float v, unsigned short& h, unsigned short& l){
  h = f2bf(v);
  l = f2bf(v - bf2f(h));
}
__device__ __forceinline__ void store_hl(unsigned short* H, unsigned short* L,
                                         size_t base, float4 v){
  us4 h, l; unsigned short hh, ll;
  split2(v.x, hh, ll); h[0]=hh; l[0]=ll;
  split2(v.y, hh, ll); h[1]=hh; l[1]=ll;
  split2(v.z, hh, ll); h[2]=hh; l[2]=ll;
  split2(v.w, hh, ll); h[3]=hh; l[3]=ll;
  *(us4*)&H[base] = h;
  *(us4*)&L[base] = l;
}
__device__ __forceinline__ float4 load_hl(const unsigned short* __restrict__ H,
                                          const unsigned short* __restrict__ L, size_t base){
  us4 h = *(const us4*)&H[base];
  us4 l = *(const us4*)&L[base];
  return make_float4(bf2f(h[0])+bf2f(l[0]), bf2f(h[1])+bf2f(l[1]),
                     bf2f(h[2])+bf2f(l[2]), bf2f(h[3])+bf2f(l[3]));
}
__device__ __forceinline__ void gl_lds16(const unsigned short* g, unsigned short* l){
  __builtin_amdgcn_global_load_lds(
      (const __attribute__((address_space(1))) unsigned int*)g,
      (__attribute__((address_space(3))) unsigned int*)l, 16, 0, 0);
}

// ============ conversions descriptor (weights only; x0 handled by k_gcn_pre0) ============
struct AllConv {
  const float* src[7];
  unsigned short* dh[7];
  unsigned short* dl[7];
  int K[7], Mm[7], Kp[7], tot[7];
};

// ===== merged: edge count (blocks [0,CNT_BLKS)) + weight conversions (rest) =====
__global__ void k_count_conv(const int* __restrict__ dst, int* __restrict__ cnt,
                             AllConv a, int convTot){
  int bid = blockIdx.x;
  if (bid < CNT_BLKS){
    int e = bid*256 + threadIdx.x;
    if (e < NE) atomicAdd(&cnt[dst[e]], 1);
  } else {
    int idx = (bid - CNT_BLKS)*256 + threadIdx.x;
    if (idx >= convTot) return;
    int j = 0;
    while (idx >= a.tot[j]){ idx -= a.tot[j]; j++; }
    int Kp = a.Kp[j], K = a.K[j], M = a.Mm[j];
    int kk = idx % Kp, m = idx / Kp;
    float v = (kk < K) ? a.src[j][(size_t)kk*M + m] : 0.f;
    unsigned short h, l; split2(v, h, l);
    a.dh[j][idx] = h; a.dl[j][idx] = l;
  }
}
__global__ void k_scan1(const int* __restrict__ cnt, int* __restrict__ bsum,
                        const int* __restrict__ batch, int* __restrict__ starts){
  __shared__ int red[256];
  int blk = blockIdx.x, t = threadIdx.x;
  int idx = blk*256 + t;
  red[t] = (idx < NN) ? cnt[idx] : 0;
  __syncthreads();
  for (int o = 128; o > 0; o >>= 1){
    if (t < o) red[t] += red[t + o];
    __syncthreads();
  }
  if (t == 0) bsum[blk] = red[0];
  if (blk == 0 && t <= NB){
    int lo = 0, hi = NN;
    while (lo < hi){ int mid = (lo + hi) >> 1; if (batch[mid] < t) lo = mid + 1; else hi = mid; }
    starts[t] = lo;
  }
}
__global__ void k_scan3(const int* __restrict__ cnt, const int* __restrict__ bsum,
                        int* __restrict__ rowptr, float* __restrict__ dinv,
                        int* __restrict__ cursor, float* __restrict__ apre){
  __shared__ int s[256];
  __shared__ int base_s;
  int blk = blockIdx.x, t = threadIdx.x;
  int idx = blk*256 + t;
  int c = (idx < NN) ? cnt[idx] : 0;
  s[t] = c;
  if (t == 0){
    int acc = 0;
    for (int i = 0; i < blk; i++) acc += bsum[i];
    base_s = acc;
    if (blk == SCAN_BLKS - 1){
      int tot = acc;
      for (int i = blk; i < SCAN_BLKS; i++) tot += bsum[i];
      rowptr[NN] = tot;
    }
  }
  __syncthreads();
  for (int o = 1; o < 256; o <<= 1){
    int v = 0;
    if (t >= o) v = s[t - o];
    __syncthreads();
    if (t >= o) s[t] += v;
    __syncthreads();
  }
  if (idx < NN){
    rowptr[idx] = base_s + s[t] - c;
    dinv[idx] = rsqrtf((float)c + 1.f);
    cursor[idx] = 0;
    apre[idx] = 0.f;
  }
}
__global__ void k_fill(const int* __restrict__ src, const int* __restrict__ dst,
                       const int* __restrict__ rowptr, int* __restrict__ cursor,
                       int* __restrict__ colidx){
  int e = blockIdx.x*blockDim.x + threadIdx.x;
  if (e >= NE) return;
  int d = dst[e];
  int pos = atomicAdd(&cursor[d], 1);
  colidx[rowptr[d] + pos] = src[e];
}

// ===== GEMM: C[N,M] = (Ah+Al)[N,Kp] @ (Bh+Bl)^T, bf16x3, m97-style =====
#define GBM 64
#define GBN 128
#define GBK 32
__global__ __launch_bounds__(256) void k_gemm_bf3(
    const unsigned short* __restrict__ Ah, const unsigned short* __restrict__ Al,
    const unsigned short* __restrict__ Bh, const unsigned short* __restrict__ Bl,
    float* __restrict__ C, int N, int Kp, int M, int mode,
    const float* __restrict__ bias, unsigned short* __restrict__ outH,
    unsigned short* __restrict__ outL,
    const float* __restrict__ a_s, const float* __restrict__ a_d,
    float* __restrict__ as_o, float* __restrict__ ad_o, int Cdim){
  __shared__ unsigned short AsH[GBM*GBK], AsL[GBM*GBK];
  __shared__ unsigned short BsH[GBN*GBK], BsL[GBN*GBK];
  __shared__ float sred[2][GBM][4];
  int gx = M / GBN;
  int gy = (N + GBM - 1) / GBM;
  const int G = 8;
  int bid = blockIdx.x;
  int full = gy / G;
  int bid_full = full * G * gx;
  int by, bx;
  if (bid < bid_full){
    int g = bid / (G*gx); int rem = bid % (G*gx);
    by = g*G + rem % G; bx = rem / G;
  } else {
    int rem = bid - bid_full; int rows = gy - full*G;
    by = full*G + rem % rows; bx = rem / rows;
  }
  int row0 = by * GBM, col0 = bx * GBN;
  int t = threadIdx.x;
  int w = t >> 6, L = t & 63;
  int lm = L & 15, lq = L >> 4;
  int wc = w * 32;

  int sr = L >> 2, sc = L & 3;
  int art = w*16 + sr;
  int ga  = (sc - ((art >> 1) & 3)) & 3;
  int agrow = min(row0 + art, N-1);
  int brt0 = w*16 + sr;
  int brt1 = (w+4)*16 + sr;
  int gb0 = (sc - ((brt0 >> 1) & 3)) & 3;
  int gb1 = (sc - ((brt1 >> 1) & 3)) & 3;
  int bgrow0 = col0 + brt0, bgrow1 = col0 + brt1;

  int rc = (lq + (lm >> 1)) & 3;
  int aoff[4], boff[2];
#pragma unroll
  for (int mi = 0; mi < 4; mi++) aoff[mi] = (mi*16 + lm)*32 + rc*8;
#pragma unroll
  for (int ni = 0; ni < 2; ni++) boff[ni] = (wc + ni*16 + lm)*32 + rc*8;

  f32x4 acc[4][2];
#pragma unroll
  for (int i = 0; i < 4; i++)
#pragma unroll
    for (int j = 0; j < 2; j++) acc[i][j] = (f32x4){0.f,0.f,0.f,0.f};

  int nk = Kp / GBK;
  for (int kt = 0; kt < nk; kt++){
    int k0 = kt * GBK;
    if (kt) __syncthreads();
    gl_lds16(&Ah[(size_t)agrow*Kp + k0 + ga*8],  &AsH[w*512]);
    gl_lds16(&Al[(size_t)agrow*Kp + k0 + ga*8],  &AsL[w*512]);
    gl_lds16(&Bh[(size_t)bgrow0*Kp + k0 + gb0*8], &BsH[w*512]);
    gl_lds16(&Bh[(size_t)bgrow1*Kp + k0 + gb1*8], &BsH[(w+4)*512]);
    gl_lds16(&Bl[(size_t)bgrow0*Kp + k0 + gb0*8], &BsL[w*512]);
    gl_lds16(&Bl[(size_t)bgrow1*Kp + k0 + gb1*8], &BsL[(w+4)*512]);
    __syncthreads();

    short8 ah[4], al[4], bh[2], bl[2];
#pragma unroll
    for (int mi = 0; mi < 4; mi++){
      ah[mi] = *(const short8*)&AsH[aoff[mi]];
      al[mi] = *(const short8*)&AsL[aoff[mi]];
    }
#pragma unroll
    for (int ni = 0; ni < 2; ni++){
      bh[ni] = *(const short8*)&BsH[boff[ni]];
      bl[ni] = *(const short8*)&BsL[boff[ni]];
    }
#pragma unroll
    for (int mi = 0; mi < 4; mi++)
#pragma unroll
      for (int ni = 0; ni < 2; ni++){
        acc[mi][ni] = __builtin_amdgcn_mfma_f32_16x16x32_bf16(ah[mi], bh[ni], acc[mi][ni], 0, 0, 0);
        acc[mi][ni] = __builtin_amdgcn_mfma_f32_16x16x32_bf16(ah[mi], bl[ni], acc[mi][ni], 0, 0, 0);
        acc[mi][ni] = __builtin_amdgcn_mfma_f32_16x16x32_bf16(al[mi], bh[ni], acc[mi][ni], 0, 0, 0);
      }
  }
  if (mode == 1){
#pragma unroll
    for (int mi = 0; mi < 4; mi++)
#pragma unroll
      for (int ni = 0; ni < 2; ni++){
#pragma unroll
        for (int r = 0; r < 4; r++){
          int row = row0 + mi*16 + lq*4 + r;
          int col = col0 + wc + ni*16 + lm;
          if (row < N){
            float v = fmaxf(acc[mi][ni][r] + bias[col], 0.f);
            unsigned short hh, ll; split2(v, hh, ll);
            outH[(size_t)row*M + col] = hh;
            outL[(size_t)row*M + col] = ll;
          }
        }
      }
  } else if (mode != 3){
#pragma unroll
    for (int mi = 0; mi < 4; mi++)
#pragma unroll
      for (int ni = 0; ni < 2; ni++){
#pragma unroll
        for (int r = 0; r < 4; r++){
          int row = row0 + mi*16 + lq*4 + r;
          int col = col0 + wc + ni*16 + lm;
          if (row < N) C[(size_t)row*M + col] = acc[mi][ni][r];
        }
      }
  }
  if (mode == 2){
    float sA0 = a_s[col0 + wc + lm], sA1 = a_s[col0 + wc + 16 + lm];
    float dA0 = a_d[col0 + wc + lm], dA1 = a_d[col0 + wc + 16 + lm];
#pragma unroll
    for (int mi = 0; mi < 4; mi++)
#pragma unroll
      for (int r = 0; r < 4; r++){
        float vs = acc[mi][0][r]*sA0 + acc[mi][1][r]*sA1;
        float vd = acc[mi][0][r]*dA0 + acc[mi][1][r]*dA1;
#pragma unroll
        for (int o = 1; o <= 8; o <<= 1){
          vs += __shfl_xor(vs, o);
          vd += __shfl_xor(vd, o);
        }
        if (lm == 0){
          int row = mi*16 + lq*4 + r;
          sred[0][row][w] = vs;
          sred[1][row][w] = vd;
        }
      }
    __syncthreads();
    if (t < GBM){
      int n = row0 + t;
      if (n < N){
        int wph = Cdim >> 5;
        int nheads = 4 / wph;
        for (int g = 0; g < nheads; g++){
          float ss = 0.f, dd = 0.f;
          for (int q = 0; q < wph; q++){
            ss += sred[0][t][g*wph + q];
            dd += sred[1][t][g*wph + q];
          }
          int hd = (col0 + g*wph*32) / Cdim;
          as_o[n*NH + hd] = ss;
          ad_o[n*NH + hd] = dd;
        }
      }
    }
  } else if (mode == 3){
    float b0 = bias[col0 + wc + lm], b1v = bias[col0 + wc + 16 + lm];
    float w0v = a_s[col0 + wc + lm], w1v = a_s[col0 + wc + 16 + lm];
#pragma unroll
    for (int mi = 0; mi < 4; mi++)
#pragma unroll
      for (int r = 0; r < 4; r++){
        float v = tanhf(acc[mi][0][r] + b0)*w0v + tanhf(acc[mi][1][r] + b1v)*w1v;
#pragma unroll
        for (int o = 1; o <= 8; o <<= 1) v += __shfl_xor(v, o);
        if (lm == 0) sred[0][mi*16 + lq*4 + r][w] = v;
      }
    __syncthreads();
    if (t < GBM){
      int n = row0 + t;
      if (n < N){
        float s = sred[0][t][0] + sred[0][t][1] + sred[0][t][2] + sred[0][t][3];
        atomicAdd(&as_o[n], s);
      }
    }
  }
}

// ===== GCN pre-agg layer 0: fp32 x0 direct, 4-way (proven round-14 config) =====
__global__ __launch_bounds__(256) void k_gcn_pre0(
    const float* __restrict__ x0, const float* __restrict__ dinv,
    const int* __restrict__ rowptr, const int* __restrict__ colidx,
    unsigned short* __restrict__ outH, unsigned short* __restrict__ outL){
  int t = threadIdx.x;
  int sub = t & 15;
  int n = blockIdx.x*16 + (t >> 4);
  if (n >= NN) return;
  int f0 = sub*4;
  bool act = f0 < 36;
  int b = rowptr[n], e = rowptr[n+1];
  float dn = dinv[n];
  float4 a0 = make_float4(0,0,0,0), a1 = make_float4(0,0,0,0);
  float4 a2 = make_float4(0,0,0,0), a3 = make_float4(0,0,0,0);
  if (act){
    int j = b;
    for (; j + 3 < e; j += 4){
      int s0 = colidx[j], s1 = colidx[j+1], s2 = colidx[j+2], s3 = colidx[j+3];
      float w0 = dinv[s0], w1 = dinv[s1], w2 = dinv[s2], w3 = dinv[s3];
      float4 v0 = *(const float4*)&x0[(size_t)s0*36 + f0];
      float4 v1 = *(const float4*)&x0[(size_t)s1*36 + f0];
      float4 v2 = *(const float4*)&x0[(size_t)s2*36 + f0];
      float4 v3 = *(const float4*)&x0[(size_t)s3*36 + f0];
      fma4(a0, v0, w0*dn); fma4(a1, v1, w1*dn);
      fma4(a2, v2, w2*dn); fma4(a3, v3, w3*dn);
    }
    for (; j < e; j++){
      int s = colidx[j];
      float4 v = *(const float4*)&x0[(size_t)s*36 + f0];
      fma4(a0, v, dinv[s]*dn);
    }
  }
  float4 acc = make_float4(a0.x+a1.x+a2.x+a3.x, a0.y+a1.y+a2.y+a3.y,
                           a0.z+a1.z+a2.z+a3.z, a0.w+a1.w+a2.w+a3.w);
  if (act){
    float4 sv = *(const float4*)&x0[(size_t)n*36 + f0];
    float dn2 = dn*dn;
    acc.x += sv.x*dn2; acc.y += sv.y*dn2; acc.z += sv.z*dn2; acc.w += sv.w*dn2;
  }
  store_hl(outH, outL, (size_t)n*64 + f0, acc);
}

// ===== GCN pre-agg (layers 1..2): 4-way (proven round-14 config) =====
__global__ __launch_bounds__(256) void k_gcn_pre(
    const unsigned short* __restrict__ inH, const unsigned short* __restrict__ inL,
    const float* __restrict__ dinv,
    const int* __restrict__ rowptr, const int* __restrict__ colidx,
    unsigned short* __restrict__ outH, unsigned short* __restrict__ outL,
    int Kp, int nchunk){
  int bid = blockIdx.x;
  int chunk = bid % nchunk, grp = bid / nchunk;
  int t = threadIdx.x;
  int sub = t & 15;
  int n = grp*16 + (t >> 4);
  if (n >= NN) return;
  int f0 = chunk*64 + sub*4;
  int b = rowptr[n], e = rowptr[n+1];
  float dn = dinv[n];
  float4 a0 = make_float4(0,0,0,0), a1 = make_float4(0,0,0,0);
  float4 a2 = make_float4(0,0,0,0), a3 = make_float4(0,0,0,0);
  int j = b;
  for (; j + 3 < e; j += 4){
    int s0 = colidx[j], s1 = colidx[j+1], s2 = colidx[j+2], s3 = colidx[j+3];
    float w0 = dinv[s0], w1 = dinv[s1], w2 = dinv[s2], w3 = dinv[s3];
    float4 v0 = load_hl(inH, inL, (size_t)s0*Kp + f0);
    float4 v1 = load_hl(inH, inL, (size_t)s1*Kp + f0);
    float4 v2 = load_hl(inH, inL, (size_t)s2*Kp + f0);
    float4 v3 = load_hl(inH, inL, (size_t)s3*Kp + f0);
    fma4(a0, v0, w0*dn); fma4(a1, v1, w1*dn);
    fma4(a2, v2, w2*dn); fma4(a3, v3, w3*dn);
  }
  for (; j < e; j++){
    int s = colidx[j];
    float4 v = load_hl(inH, inL, (size_t)s*Kp + f0);
    fma4(a0, v, dinv[s]*dn);
  }
  float4 acc = make_float4(a0.x+a1.x+a2.x+a3.x, a0.y+a1.y+a2.y+a3.y,
                           a0.z+a1.z+a2.z+a3.z, a0.w+a1.w+a2.w+a3.w);
  float4 sv = load_hl(inH, inL, (size_t)n*Kp + f0);
  float dn2 = dn*dn;
  acc.x += sv.x*dn2; acc.y += sv.y*dn2; acc.z += sv.z*dn2; acc.w += sv.w*dn2;
  store_hl(outH, outL, (size_t)n*Kp + f0, acc);
}

// ===== GAT gather: lane-cooperative online softmax. W lanes of a head-group
//       each compute ONE edge's logit/exp (1 expf per edge total, not W);
//       group max/sum via shfl_xor; (src,weight) broadcast via shfl. Exact. =====
template<int W>
__global__ __launch_bounds__(256) void k_gat_gather(
    const float* __restrict__ hg,
    const unsigned short* __restrict__ inH, const unsigned short* __restrict__ inL,
    const int* __restrict__ rowptr, const int* __restrict__ colidx,
    const float* __restrict__ as_, const float* __restrict__ ad_,
    const float* __restrict__ ab,
    unsigned short* __restrict__ outH, unsigned short* __restrict__ outL,
    int M, int C, int nchunk){
  int bid = blockIdx.x;
  int chunk = bid % nchunk, grp = bid / nchunk;
  int t = threadIdx.x;
  int sub = t & 15;
  int n = grp*16 + (t >> 4);
  if (n >= NN) return;
  int f0 = chunk*64 + sub*4;
  int hd = f0 / C;
  int lg = sub & (W - 1);
  int b = rowptr[n], e = rowptr[n+1];
  int ai = n*NH + hd;
  float adn = ad_[ai];
  float selflog = leakyf(as_[ai] + adn);
  float m = selflog, d = 1.f;
  float4 A0 = make_float4(0,0,0,0), A1 = make_float4(0,0,0,0);
  float4 A2 = make_float4(0,0,0,0), A3 = make_float4(0,0,0,0);
  int j0 = b;
  for (; j0 + W <= e; j0 += W){
    int sE = colidx[j0 + lg];
    float lE = leakyf(as_[sE*NH + hd] + adn);
    float mb = lE;
#pragma unroll
    for (int o = 1; o < W; o <<= 1) mb = fmaxf(mb, __shfl_xor(mb, o, W));
    if (mb > m){
      float sc = expf(m - mb);
      d *= sc; mul4(A0, sc); mul4(A1, sc); mul4(A2, sc); mul4(A3, sc);
      m = mb;
    }
    float wE = expf(lE - m);
    float ds = wE;
#pragma unroll
    for (int o = 1; o < W; o <<= 1) ds += __shfl_xor(ds, o, W);
    d += ds;
#pragma unroll
    for (int q = 0; q < W; q += 4){
      int   s0 = __shfl(sE, q,   W), s1 = __shfl(sE, q+1, W);
      int   s2 = __shfl(sE, q+2, W), s3 = __shfl(sE, q+3, W);
      float w0 = __shfl(wE, q,   W), w1 = __shfl(wE, q+1, W);
      float w2 = __shfl(wE, q+2, W), w3 = __shfl(wE, q+3, W);
      float4 v0 = *(const float4*)&hg[(size_t)s0*M + f0];
      float4 v1 = *(const float4*)&hg[(size_t)s1*M + f0];
      float4 v2 = *(const float4*)&hg[(size_t)s2*M + f0];
      float4 v3 = *(const float4*)&hg[(size_t)s3*M + f0];
      fma4(A0, v0, w0); fma4(A1, v1, w1);
      fma4(A2, v2, w2); fma4(A3, v3, w3);
    }
  }
  // tail (< W edges): per-lane identical path
  for (; j0 < e; j0++){
    int s = colidx[j0];
    float l = leakyf(as_[s*NH + hd] + adn);
    float4 v = *(const float4*)&hg[(size_t)s*M + f0];
    if (l > m){
      float sc = expf(m - l);
      d *= sc; mul4(A0, sc); mul4(A1, sc); mul4(A2, sc); mul4(A3, sc);
      m = l;
    }
    float ww = expf(l - m);
    d += ww;
    fma4(A0, v, ww);
  }
  float4 acc = make_float4(A0.x+A1.x+A2.x+A3.x, A0.y+A1.y+A2.y+A3.y,
                           A0.z+A1.z+A2.z+A3.z, A0.w+A1.w+A2.w+A3.w);
  float es = expf(selflog - m), inv = 1.f/d;
  float4 sv = *(const float4*)&hg[(size_t)n*M + f0];
  float4 hv = load_hl(inH, inL, (size_t)n*M + f0);
  float4 bb = *(const float4*)&ab[f0];
  float4 r = make_float4(
    hv.x + bb.x + (sv.x*es + acc.x)*inv,
    hv.y + bb.y + (sv.y*es + acc.y)*inv,
    hv.z + bb.z + (sv.z*es + acc.z)*inv,
    hv.w + bb.w + (sv.w*es + acc.w)*inv);
  store_hl(outH, outL, (size_t)n*M + f0, r);
}

// ================= attention pooling (fused prep + gather) =================
__global__ void k_pool(const unsigned short* __restrict__ xH, const unsigned short* __restrict__ xL,
                       const float* __restrict__ apre, const int* __restrict__ starts,
                       float* __restrict__ out){
  __shared__ float red[128];
  int g = blockIdx.x, t = threadIdx.x;
  int b = starts[g], e = starts[g+1];
  float m = -INFINITY;
  for (int n = b + t; n < e; n += 128) m = fmaxf(m, apre[n]);
  red[t] = m; __syncthreads();
  for (int o = 64; o > 0; o >>= 1){
    if (t < o) red[t] = fmaxf(red[t], red[t + o]);
    __syncthreads();
  }
  m = red[0]; __syncthreads();
  float s = 0.f;
  for (int n = b + t; n < e; n += 128) s += expf(apre[n] - m);
  red[t] = s; __syncthreads();
  for (int o = 64; o > 0; o >>= 1){
    if (t < o) red[t] += red[t + o];
    __syncthreads();
  }
  float inv = 1.f / (red[0] + 1e-8f);
  float4 sum = make_float4(0,0,0,0), wacc = make_float4(0,0,0,0);
  float4 mx = make_float4(-INFINITY,-INFINITY,-INFINITY,-INFINITY);
  for (int n = b; n < e; n++){
    float4 xv = load_hl(xH, xL, (size_t)n*DOUT + t*4);
    float p = expf(apre[n] - m) * inv;
    sum.x += xv.x; sum.y += xv.y; sum.z += xv.z; sum.w += xv.w;
    mx.x = fmaxf(mx.x, xv.x); mx.y = fmaxf(mx.y, xv.y);
    mx.z = fmaxf(mx.z, xv.z); mx.w = fmaxf(mx.w, xv.w);
    fma4(wacc, xv, p);
  }
  float ic = 1.f / fmaxf((float)(e - b), 1.f);
  float4* o = (float4*)(out + (size_t)g*4*DOUT);
  o[t]       = wacc;
  o[128 + t] = make_float4(sum.x*ic, sum.y*ic, sum.z*ic, sum.w*ic);
  o[256 + t] = mx;
  o[384 + t] = sum;
}

extern "C" void kernel_launch(void* const* d_in, const int* in_sizes, int n_in,
                              void* d_out, int out_size, void* d_ws, size_t ws_size,
                              hipStream_t stream) {
  const float* x0   = (const float*)d_in[0];
  const int*   ei   = (const int*)d_in[1];
  const int*   src  = ei;
  const int*   dst  = ei + NE;
  const int*   batch= (const int*)d_in[2];
  const float* gw[3]  = {(const float*)d_in[3],  (const float*)d_in[9],  (const float*)d_in[15]};
  const float* gb[3]  = {(const float*)d_in[4],  (const float*)d_in[10], (const float*)d_in[16]};
  const float* aw[3]  = {(const float*)d_in[5],  (const float*)d_in[11], (const float*)d_in[17]};
  const float* asw[3] = {(const float*)d_in[6],  (const float*)d_in[12], (const float*)d_in[18]};
  const float* adw[3] = {(const float*)d_in[7],  (const float*)d_in[13], (const float*)d_in[19]};
  const float* ab[3]  = {(const float*)d_in[8],  (const float*)d_in[14], (const float*)d_in[20]};
  const float* apw1 = (const float*)d_in[21];
  const float* apb1 = (const float*)d_in[22];
  const float* apw2 = (const float*)d_in[23];
  float* out = (float*)d_out;

  // ---- workspace carve ----
  char* p = (char*)d_ws;
  auto alloc = [&](size_t bytes) -> void* {
    void* r = (void*)p; p += (bytes + 255) & ~(size_t)255; return r;
  };
  float* f1 = (float*)alloc((size_t)NN*512*4);
  unsigned short* actH0 = (unsigned short*)alloc((size_t)NN*512*2);
  unsigned short* actL0 = (unsigned short*)alloc((size_t)NN*512*2);
  unsigned short* actH1 = (unsigned short*)alloc((size_t)NN*512*2);
  unsigned short* actL1 = (unsigned short*)alloc((size_t)NN*512*2);
  unsigned short* preH  = (unsigned short*)alloc((size_t)NN*256*2);
  unsigned short* preL  = (unsigned short*)alloc((size_t)NN*256*2);
  const int wK[7]  = {36, 128, 128, 256, 256, 512, 512};
  const int wM[7]  = {128, 128, 256, 256, 512, 512, 256};
  const int wKp[7] = {64, 128, 128, 256, 256, 512, 512};
  const float* wsrc[7] = {gw[0], aw[0], gw[1], aw[1], gw[2], aw[2], apw1};
  unsigned short* wTh[7]; unsigned short* wTl[7];
  for (int i = 0; i < 7; i++){
    size_t sz = (size_t)wM[i]*wKp[i]*2;
    wTh[i] = (unsigned short*)alloc(sz);
    wTl[i] = (unsigned short*)alloc(sz);
  }
  float* dinv = (float*)alloc(NN*4);
  float* as_  = (float*)alloc(NN*NH*4);
  float* ad_  = (float*)alloc(NN*NH*4);
  float* apre = (float*)alloc(NN*4);
  int* rowptr = (int*)alloc((NN+1)*4);
  int* colidx = (int*)alloc((size_t)NE*4);
  int* cnt    = (int*)alloc(NN*4);
  int* cursor = (int*)alloc(NN*4);
  int* starts = (int*)alloc((NB+1)*4);
  int* bsum   = (int*)alloc(SCAN_BLKS*4);

  // ---- conv descriptor (weights only) ----
  AllConv ac;
  int convTot = 0;
  for (int i = 0; i < 7; i++){
    ac.src[i] = wsrc[i]; ac.dh[i] = wTh[i]; ac.dl[i] = wTl[i];
    ac.K[i] = wK[i]; ac.Mm[i] = wM[i]; ac.Kp[i] = wKp[i];
    ac.tot[i] = wKp[i]*wM[i];
    convTot += ac.tot[i];
  }

  // ---- CSR build (count merged with conversions) -> scans -> fill ----
  hipMemsetAsync(cnt, 0, NN*sizeof(int), stream);
  int convBlks = (convTot + 255) / 256;
  k_count_conv<<<CNT_BLKS + convBlks, 256, 0, stream>>>(dst, cnt, ac, convTot);
  k_scan1<<<SCAN_BLKS, 256, 0, stream>>>(cnt, bsum, batch, starts);
  k_scan3<<<SCAN_BLKS, 256, 0, stream>>>(cnt, bsum, rowptr, dinv, cursor, apre);
  k_fill<<<(NE+255)/256, 256, 0, stream>>>(src, dst, rowptr, cursor, colidx);

  const int dims[4] = {36, 128, 256, 512};
  const int ngrp = (NN + 15) / 16;
  const unsigned short* curH = nullptr; const unsigned short* curL = nullptr;
  int wi = 0;
  for (int i = 0; i < 3; i++){
    int Kin = (i == 0) ? 64 : dims[i];
    int M = dims[i+1], C = M/NH;
    int nchunk_in = Kin / 64;
    int nchunk = M / 64;
    int nblk = (M/GBN) * ((NN+GBM-1)/GBM);
    if (i == 0){
      k_gcn_pre0<<<ngrp, 256, 0, stream>>>(x0, dinv, rowptr, colidx, preH, preL);
    } else {
      k_gcn_pre<<<nchunk_in*ngrp, 256, 0, stream>>>(curH, curL, dinv, rowptr, colidx,
                                                    preH, preL, Kin, nchunk_in);
    }
    k_gemm_bf3<<<nblk, 256, 0, stream>>>(preH, preL, wTh[wi], wTl[wi], f1, NN, wKp[wi], M,
                                         1, gb[i], actH0, actL0,
                                         nullptr, nullptr, nullptr, nullptr, C);
    wi++;
    k_gemm_bf3<<<nblk, 256, 0, stream>>>(actH0, actL0, wTh[wi], wTl[wi], f1, NN, wKp[wi], M,
                                         2, nullptr, nullptr, nullptr,
                                         asw[i], adw[i], as_, ad_, C);
    wi++;
    if (C >= 64){
      k_gat_gather<16><<<nchunk*ngrp, 256, 0, stream>>>(f1, actH0, actL0, rowptr, colidx,
                                                        as_, ad_, ab[i],
                                                        actH1, actL1, M, C, nchunk);
    } else {
      k_gat_gather<8><<<nchunk*ngrp, 256, 0, stream>>>(f1, actH0, actL0, rowptr, colidx,
                                                       as_, ad_, ab[i],
                                                       actH1, actL1, M, C, nchunk);
    }
    curH = actH1; curL = actL1;
  }

  // ---- pooling ----
  {
    int nblk = (256/GBN) * ((NN+GBM-1)/GBM);
    k_gemm_bf3<<<nblk, 256, 0, stream>>>(actH1, actL1, wTh[6], wTl[6], f1, NN, wKp[6], 256,
                                         3, apb1, nullptr, nullptr,
                                         apw2, nullptr, apre, nullptr, 64);
  }
  k_pool<<<NB, 128, 0, stream>>>(actH1, actL1, apre, starts, out);
}

// Round 17
// 397.555 us; speedup vs baseline: 1.0640x; 1.0640x over previous
//
#include <hip/hip_runtime.h>
#include <math.h>

#define NN 10000
#define NE 160000
#define NB 128
#define NH 4
#define DOUT 512
#define NEG 0.2f
#define SCAN_BLKS ((NN + 255) / 256)   // 40
#define CNT_BLKS ((NE + 255) / 256)    // 625

typedef __attribute__((ext_vector_type(8))) short short8;
typedef __attribute__((ext_vector_type(4))) float f32x4;
typedef __attribute__((ext_vector_type(4))) unsigned short us4;

__device__ __forceinline__ float leakyf(float v){ return v > 0.f ? v : NEG*v; }
__device__ __forceinline__ void fma4(float4& a, const float4 v, float w){
  a.x += v.x*w; a.y += v.y*w; a.z += v.z*w; a.w += v.w*w;
}
__device__ __forceinline__ void mul4(float4& a, float s){
  a.x *= s; a.y *= s; a.z *= s; a.w *= s;
}
__device__ __forceinline__ unsigned short f2bf(float f){
  unsigned int u = __float_as_uint(f);
  u += 0x7FFFu + ((u >> 16) & 1u);
  return (unsigned short)(u >> 16);
}
__device__ __forceinline__ float bf2f(unsigned short h){
  return __uint_as_float(((unsigned int)h) << 16);
}
__device__ __forceinline__ void split2(float v, unsigned short& h, unsigned short& l){
  h = f2bf(v);
  l = f2bf(v - bf2f(h));
}
__device__ __forceinline__ void store_hl(unsigned short* H, unsigned short* L,
                                         size_t base, float4 v){
  us4 h, l; unsigned short hh, ll;
  split2(v.x, hh, ll); h[0]=hh; l[0]=ll;
  split2(v.y, hh, ll); h[1]=hh; l[1]=ll;
  split2(v.z, hh, ll); h[2]=hh; l[2]=ll;
  split2(v.w, hh, ll); h[3]=hh; l[3]=ll;
  *(us4*)&H[base] = h;
  *(us4*)&L[base] = l;
}
__device__ __forceinline__ float4 load_hl(const unsigned short* __restrict__ H,
                                          const unsigned short* __restrict__ L, size_t base){
  us4 h = *(const us4*)&H[base];
  us4 l = *(const us4*)&L[base];
  return make_float4(bf2f(h[0])+bf2f(l[0]), bf2f(h[1])+bf2f(l[1]),
                     bf2f(h[2])+bf2f(l[2]), bf2f(h[3])+bf2f(l[3]));
}
__device__ __forceinline__ void gl_lds16(const unsigned short* g, unsigned short* l){
  __builtin_amdgcn_global_load_lds(
      (const __attribute__((address_space(1))) unsigned int*)g,
      (__attribute__((address_space(3))) unsigned int*)l, 16, 0, 0);
}

// ============ conversions descriptor (weights only; x0 handled by k_gcn_pre0) ============
struct AllConv {
  const float* src[7];
  unsigned short* dh[7];
  unsigned short* dl[7];
  int K[7], Mm[7], Kp[7], tot[7];
};

// ===== merged: edge count (blocks [0,CNT_BLKS)) + weight conversions (rest) =====
__global__ void k_count_conv(const int* __restrict__ dst, int* __restrict__ cnt,
                             AllConv a, int convTot){
  int bid = blockIdx.x;
  if (bid < CNT_BLKS){
    int e = bid*256 + threadIdx.x;
    if (e < NE) atomicAdd(&cnt[dst[e]], 1);
  } else {
    int idx = (bid - CNT_BLKS)*256 + threadIdx.x;
    if (idx >= convTot) return;
    int j = 0;
    while (idx >= a.tot[j]){ idx -= a.tot[j]; j++; }
    int Kp = a.Kp[j], K = a.K[j], M = a.Mm[j];
    int kk = idx % Kp, m = idx / Kp;
    float v = (kk < K) ? a.src[j][(size_t)kk*M + m] : 0.f;
    unsigned short h, l; split2(v, h, l);
    a.dh[j][idx] = h; a.dl[j][idx] = l;
  }
}
__global__ void k_scan1(const int* __restrict__ cnt, int* __restrict__ bsum,
                        const int* __restrict__ batch, int* __restrict__ starts){
  __shared__ int red[256];
  int blk = blockIdx.x, t = threadIdx.x;
  int idx = blk*256 + t;
  red[t] = (idx < NN) ? cnt[idx] : 0;
  __syncthreads();
  for (int o = 128; o > 0; o >>= 1){
    if (t < o) red[t] += red[t + o];
    __syncthreads();
  }
  if (t == 0) bsum[blk] = red[0];
  if (blk == 0 && t <= NB){
    int lo = 0, hi = NN;
    while (lo < hi){ int mid = (lo + hi) >> 1; if (batch[mid] < t) lo = mid + 1; else hi = mid; }
    starts[t] = lo;
  }
}
__global__ void k_scan3(const int* __restrict__ cnt, const int* __restrict__ bsum,
                        int* __restrict__ rowptr, float* __restrict__ dinv,
                        int* __restrict__ cursor, float* __restrict__ apre){
  __shared__ int s[256];
  __shared__ int base_s;
  int blk = blockIdx.x, t = threadIdx.x;
  int idx = blk*256 + t;
  int c = (idx < NN) ? cnt[idx] : 0;
  s[t] = c;
  if (t == 0){
    int acc = 0;
    for (int i = 0; i < blk; i++) acc += bsum[i];
    base_s = acc;
    if (blk == SCAN_BLKS - 1){
      int tot = acc;
      for (int i = blk; i < SCAN_BLKS; i++) tot += bsum[i];
      rowptr[NN] = tot;
    }
  }
  __syncthreads();
  for (int o = 1; o < 256; o <<= 1){
    int v = 0;
    if (t >= o) v = s[t - o];
    __syncthreads();
    if (t >= o) s[t] += v;
    __syncthreads();
  }
  if (idx < NN){
    rowptr[idx] = base_s + s[t] - c;
    dinv[idx] = rsqrtf((float)c + 1.f);
    cursor[idx] = 0;
    apre[idx] = 0.f;
  }
}
__global__ void k_fill(const int* __restrict__ src, const int* __restrict__ dst,
                       const int* __restrict__ rowptr, int* __restrict__ cursor,
                       int* __restrict__ colidx){
  int e = blockIdx.x*blockDim.x + threadIdx.x;
  if (e >= NE) return;
  int d = dst[e];
  int pos = atomicAdd(&cursor[d], 1);
  colidx[rowptr[d] + pos] = src[e];
}

// ===== GEMM: C[N,M] = (Ah+Al)[N,Kp] @ (Bh+Bl)^T, bf16x3, m97-style =====
#define GBM 64
#define GBN 128
#define GBK 32
__global__ __launch_bounds__(256) void k_gemm_bf3(
    const unsigned short* __restrict__ Ah, const unsigned short* __restrict__ Al,
    const unsigned short* __restrict__ Bh, const unsigned short* __restrict__ Bl,
    float* __restrict__ C, int N, int Kp, int M, int mode,
    const float* __restrict__ bias, unsigned short* __restrict__ outH,
    unsigned short* __restrict__ outL,
    const float* __restrict__ a_s, const float* __restrict__ a_d,
    float* __restrict__ as_o, float* __restrict__ ad_o, int Cdim){
  __shared__ unsigned short AsH[GBM*GBK], AsL[GBM*GBK];
  __shared__ unsigned short BsH[GBN*GBK], BsL[GBN*GBK];
  __shared__ float sred[2][GBM][4];
  int gx = M / GBN;
  int gy = (N + GBM - 1) / GBM;
  const int G = 8;
  int bid = blockIdx.x;
  int full = gy / G;
  int bid_full = full * G * gx;
  int by, bx;
  if (bid < bid_full){
    int g = bid / (G*gx); int rem = bid % (G*gx);
    by = g*G + rem % G; bx = rem / G;
  } else {
    int rem = bid - bid_full; int rows = gy - full*G;
    by = full*G + rem % rows; bx = rem / rows;
  }
  int row0 = by * GBM, col0 = bx * GBN;
  int t = threadIdx.x;
  int w = t >> 6, L = t & 63;
  int lm = L & 15, lq = L >> 4;
  int wc = w * 32;

  int sr = L >> 2, sc = L & 3;
  int art = w*16 + sr;
  int ga  = (sc - ((art >> 1) & 3)) & 3;
  int agrow = min(row0 + art, N-1);
  int brt0 = w*16 + sr;
  int brt1 = (w+4)*16 + sr;
  int gb0 = (sc - ((brt0 >> 1) & 3)) & 3;
  int gb1 = (sc - ((brt1 >> 1) & 3)) & 3;
  int bgrow0 = col0 + brt0, bgrow1 = col0 + brt1;

  int rc = (lq + (lm >> 1)) & 3;
  int aoff[4], boff[2];
#pragma unroll
  for (int mi = 0; mi < 4; mi++) aoff[mi] = (mi*16 + lm)*32 + rc*8;
#pragma unroll
  for (int ni = 0; ni < 2; ni++) boff[ni] = (wc + ni*16 + lm)*32 + rc*8;

  f32x4 acc[4][2];
#pragma unroll
  for (int i = 0; i < 4; i++)
#pragma unroll
    for (int j = 0; j < 2; j++) acc[i][j] = (f32x4){0.f,0.f,0.f,0.f};

  int nk = Kp / GBK;
  for (int kt = 0; kt < nk; kt++){
    int k0 = kt * GBK;
    if (kt) __syncthreads();
    gl_lds16(&Ah[(size_t)agrow*Kp + k0 + ga*8],  &AsH[w*512]);
    gl_lds16(&Al[(size_t)agrow*Kp + k0 + ga*8],  &AsL[w*512]);
    gl_lds16(&Bh[(size_t)bgrow0*Kp + k0 + gb0*8], &BsH[w*512]);
    gl_lds16(&Bh[(size_t)bgrow1*Kp + k0 + gb1*8], &BsH[(w+4)*512]);
    gl_lds16(&Bl[(size_t)bgrow0*Kp + k0 + gb0*8], &BsL[w*512]);
    gl_lds16(&Bl[(size_t)bgrow1*Kp + k0 + gb1*8], &BsL[(w+4)*512]);
    __syncthreads();

    short8 ah[4], al[4], bh[2], bl[2];
#pragma unroll
    for (int mi = 0; mi < 4; mi++){
      ah[mi] = *(const short8*)&AsH[aoff[mi]];
      al[mi] = *(const short8*)&AsL[aoff[mi]];
    }
#pragma unroll
    for (int ni = 0; ni < 2; ni++){
      bh[ni] = *(const short8*)&BsH[boff[ni]];
      bl[ni] = *(const short8*)&BsL[boff[ni]];
    }
#pragma unroll
    for (int mi = 0; mi < 4; mi++)
#pragma unroll
      for (int ni = 0; ni < 2; ni++){
        acc[mi][ni] = __builtin_amdgcn_mfma_f32_16x16x32_bf16(ah[mi], bh[ni], acc[mi][ni], 0, 0, 0);
        acc[mi][ni] = __builtin_amdgcn_mfma_f32_16x16x32_bf16(ah[mi], bl[ni], acc[mi][ni], 0, 0, 0);
        acc[mi][ni] = __builtin_amdgcn_mfma_f32_16x16x32_bf16(al[mi], bh[ni], acc[mi][ni], 0, 0, 0);
      }
  }
  if (mode == 1){
#pragma unroll
    for (int mi = 0; mi < 4; mi++)
#pragma unroll
      for (int ni = 0; ni < 2; ni++){
#pragma unroll
        for (int r = 0; r < 4; r++){
          int row = row0 + mi*16 + lq*4 + r;
          int col = col0 + wc + ni*16 + lm;
          if (row < N){
            float v = fmaxf(acc[mi][ni][r] + bias[col], 0.f);
            unsigned short hh, ll; split2(v, hh, ll);
            outH[(size_t)row*M + col] = hh;
            outL[(size_t)row*M + col] = ll;
          }
        }
      }
  } else if (mode != 3){
#pragma unroll
    for (int mi = 0; mi < 4; mi++)
#pragma unroll
      for (int ni = 0; ni < 2; ni++){
#pragma unroll
        for (int r = 0; r < 4; r++){
          int row = row0 + mi*16 + lq*4 + r;
          int col = col0 + wc + ni*16 + lm;
          if (row < N) C[(size_t)row*M + col] = acc[mi][ni][r];
        }
      }
  }
  if (mode == 2){
    float sA0 = a_s[col0 + wc + lm], sA1 = a_s[col0 + wc + 16 + lm];
    float dA0 = a_d[col0 + wc + lm], dA1 = a_d[col0 + wc + 16 + lm];
#pragma unroll
    for (int mi = 0; mi < 4; mi++)
#pragma unroll
      for (int r = 0; r < 4; r++){
        float vs = acc[mi][0][r]*sA0 + acc[mi][1][r]*sA1;
        float vd = acc[mi][0][r]*dA0 + acc[mi][1][r]*dA1;
#pragma unroll
        for (int o = 1; o <= 8; o <<= 1){
          vs += __shfl_xor(vs, o);
          vd += __shfl_xor(vd, o);
        }
        if (lm == 0){
          int row = mi*16 + lq*4 + r;
          sred[0][row][w] = vs;
          sred[1][row][w] = vd;
        }
      }
    __syncthreads();
    if (t < GBM){
      int n = row0 + t;
      if (n < N){
        int wph = Cdim >> 5;
        int nheads = 4 / wph;
        for (int g = 0; g < nheads; g++){
          float ss = 0.f, dd = 0.f;
          for (int q = 0; q < wph; q++){
            ss += sred[0][t][g*wph + q];
            dd += sred[1][t][g*wph + q];
          }
          int hd = (col0 + g*wph*32) / Cdim;
          as_o[n*NH + hd] = ss;
          ad_o[n*NH + hd] = dd;
        }
      }
    }
  } else if (mode == 3){
    float b0 = bias[col0 + wc + lm], b1v = bias[col0 + wc + 16 + lm];
    float w0v = a_s[col0 + wc + lm], w1v = a_s[col0 + wc + 16 + lm];
#pragma unroll
    for (int mi = 0; mi < 4; mi++)
#pragma unroll
      for (int r = 0; r < 4; r++){
        float v = tanhf(acc[mi][0][r] + b0)*w0v + tanhf(acc[mi][1][r] + b1v)*w1v;
#pragma unroll
        for (int o = 1; o <= 8; o <<= 1) v += __shfl_xor(v, o);
        if (lm == 0) sred[0][mi*16 + lq*4 + r][w] = v;
      }
    __syncthreads();
    if (t < GBM){
      int n = row0 + t;
      if (n < N){
        float s = sred[0][t][0] + sred[0][t][1] + sred[0][t][2] + sred[0][t][3];
        atomicAdd(&as_o[n], s);
      }
    }
  }
}

// ===== GCN pre-agg layer 0: fp32 x0 direct, 4-way =====
__global__ __launch_bounds__(256) void k_gcn_pre0(
    const float* __restrict__ x0, const float* __restrict__ dinv,
    const int* __restrict__ rowptr, const int* __restrict__ colidx,
    unsigned short* __restrict__ outH, unsigned short* __restrict__ outL){
  int t = threadIdx.x;
  int sub = t & 15;
  int n = blockIdx.x*16 + (t >> 4);
  if (n >= NN) return;
  int f0 = sub*4;
  bool act = f0 < 36;
  int b = rowptr[n], e = rowptr[n+1];
  float dn = dinv[n];
  float4 a0 = make_float4(0,0,0,0), a1 = make_float4(0,0,0,0);
  float4 a2 = make_float4(0,0,0,0), a3 = make_float4(0,0,0,0);
  if (act){
    int j = b;
    for (; j + 3 < e; j += 4){
      int s0 = colidx[j], s1 = colidx[j+1], s2 = colidx[j+2], s3 = colidx[j+3];
      float w0 = dinv[s0], w1 = dinv[s1], w2 = dinv[s2], w3 = dinv[s3];
      float4 v0 = *(const float4*)&x0[(size_t)s0*36 + f0];
      float4 v1 = *(const float4*)&x0[(size_t)s1*36 + f0];
      float4 v2 = *(const float4*)&x0[(size_t)s2*36 + f0];
      float4 v3 = *(const float4*)&x0[(size_t)s3*36 + f0];
      fma4(a0, v0, w0*dn); fma4(a1, v1, w1*dn);
      fma4(a2, v2, w2*dn); fma4(a3, v3, w3*dn);
    }
    for (; j < e; j++){
      int s = colidx[j];
      float4 v = *(const float4*)&x0[(size_t)s*36 + f0];
      fma4(a0, v, dinv[s]*dn);
    }
  }
  float4 acc = make_float4(a0.x+a1.x+a2.x+a3.x, a0.y+a1.y+a2.y+a3.y,
                           a0.z+a1.z+a2.z+a3.z, a0.w+a1.w+a2.w+a3.w);
  if (act){
    float4 sv = *(const float4*)&x0[(size_t)n*36 + f0];
    float dn2 = dn*dn;
    acc.x += sv.x*dn2; acc.y += sv.y*dn2; acc.z += sv.z*dn2; acc.w += sv.w*dn2;
  }
  store_hl(outH, outL, (size_t)n*64 + f0, acc);
}

// ===== GCN pre-agg (layers 1..2): 4-way =====
__global__ __launch_bounds__(256) void k_gcn_pre(
    const unsigned short* __restrict__ inH, const unsigned short* __restrict__ inL,
    const float* __restrict__ dinv,
    const int* __restrict__ rowptr, const int* __restrict__ colidx,
    unsigned short* __restrict__ outH, unsigned short* __restrict__ outL,
    int Kp, int nchunk){
  int bid = blockIdx.x;
  int chunk = bid % nchunk, grp = bid / nchunk;
  int t = threadIdx.x;
  int sub = t & 15;
  int n = grp*16 + (t >> 4);
  if (n >= NN) return;
  int f0 = chunk*64 + sub*4;
  int b = rowptr[n], e = rowptr[n+1];
  float dn = dinv[n];
  float4 a0 = make_float4(0,0,0,0), a1 = make_float4(0,0,0,0);
  float4 a2 = make_float4(0,0,0,0), a3 = make_float4(0,0,0,0);
  int j = b;
  for (; j + 3 < e; j += 4){
    int s0 = colidx[j], s1 = colidx[j+1], s2 = colidx[j+2], s3 = colidx[j+3];
    float w0 = dinv[s0], w1 = dinv[s1], w2 = dinv[s2], w3 = dinv[s3];
    float4 v0 = load_hl(inH, inL, (size_t)s0*Kp + f0);
    float4 v1 = load_hl(inH, inL, (size_t)s1*Kp + f0);
    float4 v2 = load_hl(inH, inL, (size_t)s2*Kp + f0);
    float4 v3 = load_hl(inH, inL, (size_t)s3*Kp + f0);
    fma4(a0, v0, w0*dn); fma4(a1, v1, w1*dn);
    fma4(a2, v2, w2*dn); fma4(a3, v3, w3*dn);
  }
  for (; j < e; j++){
    int s = colidx[j];
    float4 v = load_hl(inH, inL, (size_t)s*Kp + f0);
    fma4(a0, v, dinv[s]*dn);
  }
  float4 acc = make_float4(a0.x+a1.x+a2.x+a3.x, a0.y+a1.y+a2.y+a3.y,
                           a0.z+a1.z+a2.z+a3.z, a0.w+a1.w+a2.w+a3.w);
  float4 sv = load_hl(inH, inL, (size_t)n*Kp + f0);
  float dn2 = dn*dn;
  acc.x += sv.x*dn2; acc.y += sv.y*dn2; acc.z += sv.z*dn2; acc.w += sv.w*dn2;
  store_hl(outH, outL, (size_t)n*Kp + f0, acc);
}

// ===== GAT gather: fused online-softmax (flash-style), feature-chunked,
//       XCD-aligned, 4-way edge-unrolled — round-14 proven config =====
__global__ __launch_bounds__(256) void k_gat_gather(
    const float* __restrict__ hg,
    const unsigned short* __restrict__ inH, const unsigned short* __restrict__ inL,
    const int* __restrict__ rowptr, const int* __restrict__ colidx,
    const float* __restrict__ as_, const float* __restrict__ ad_,
    const float* __restrict__ ab,
    unsigned short* __restrict__ outH, unsigned short* __restrict__ outL,
    int M, int C, int nchunk){
  int bid = blockIdx.x;
  int chunk = bid % nchunk, grp = bid / nchunk;
  int t = threadIdx.x;
  int sub = t & 15;
  int n = grp*16 + (t >> 4);
  if (n >= NN) return;
  int f0 = chunk*64 + sub*4;
  int hd = f0 / C;
  int b = rowptr[n], e = rowptr[n+1];
  int ai = n*NH + hd;
  float adn = ad_[ai];
  float selflog = leakyf(as_[ai] + adn);
  float m = selflog, d = 1.f;
  float4 a0 = make_float4(0,0,0,0), a1 = make_float4(0,0,0,0);
  float4 a2 = make_float4(0,0,0,0), a3 = make_float4(0,0,0,0);
  int j = b;
  for (; j + 3 < e; j += 4){
    int s0 = colidx[j], s1 = colidx[j+1], s2 = colidx[j+2], s3 = colidx[j+3];
    float l0 = leakyf(as_[s0*NH + hd] + adn), l1 = leakyf(as_[s1*NH + hd] + adn);
    float l2 = leakyf(as_[s2*NH + hd] + adn), l3 = leakyf(as_[s3*NH + hd] + adn);
    float4 v0 = *(const float4*)&hg[(size_t)s0*M + f0];
    float4 v1 = *(const float4*)&hg[(size_t)s1*M + f0];
    float4 v2 = *(const float4*)&hg[(size_t)s2*M + f0];
    float4 v3 = *(const float4*)&hg[(size_t)s3*M + f0];
    float m4 = fmaxf(fmaxf(l0, l1), fmaxf(l2, l3));
    if (m4 > m){
      float sc = expf(m - m4);
      d *= sc; mul4(a0, sc); mul4(a1, sc); mul4(a2, sc); mul4(a3, sc);
      m = m4;
    }
    float w0 = expf(l0 - m), w1 = expf(l1 - m);
    float w2 = expf(l2 - m), w3 = expf(l3 - m);
    d += (w0 + w1) + (w2 + w3);
    fma4(a0, v0, w0); fma4(a1, v1, w1);
    fma4(a2, v2, w2); fma4(a3, v3, w3);
  }
  for (; j < e; j++){
    int s = colidx[j];
    float l = leakyf(as_[s*NH + hd] + adn);
    float4 v = *(const float4*)&hg[(size_t)s*M + f0];
    if (l > m){
      float sc = expf(m - l);
      d *= sc; mul4(a0, sc); mul4(a1, sc); mul4(a2, sc); mul4(a3, sc);
      m = l;
    }
    float ww = expf(l - m);
    d += ww;
    fma4(a0, v, ww);
  }
  float4 acc = make_float4(a0.x+a1.x+a2.x+a3.x, a0.y+a1.y+a2.y+a3.y,
                           a0.z+a1.z+a2.z+a3.z, a0.w+a1.w+a2.w+a3.w);
  float es = expf(selflog - m), inv = 1.f/d;
  float4 sv = *(const float4*)&hg[(size_t)n*M + f0];
  float4 hv = load_hl(inH, inL, (size_t)n*M + f0);
  float4 bb = *(const float4*)&ab[f0];
  float4 r = make_float4(
    hv.x + bb.x + (sv.x*es + acc.x)*inv,
    hv.y + bb.y + (sv.y*es + acc.y)*inv,
    hv.z + bb.z + (sv.z*es + acc.z)*inv,
    hv.w + bb.w + (sv.w*es + acc.w)*inv);
  store_hl(outH, outL, (size_t)n*M + f0, r);
}

// ================= attention pooling (fused prep + gather) =================
__global__ void k_pool(const unsigned short* __restrict__ xH, const unsigned short* __restrict__ xL,
                       const float* __restrict__ apre, const int* __restrict__ starts,
                       float* __restrict__ out){
  __shared__ float red[128];
  int g = blockIdx.x, t = threadIdx.x;
  int b = starts[g], e = starts[g+1];
  float m = -INFINITY;
  for (int n = b + t; n < e; n += 128) m = fmaxf(m, apre[n]);
  red[t] = m; __syncthreads();
  for (int o = 64; o > 0; o >>= 1){
    if (t < o) red[t] = fmaxf(red[t], red[t + o]);
    __syncthreads();
  }
  m = red[0]; __syncthreads();
  float s = 0.f;
  for (int n = b + t; n < e; n += 128) s += expf(apre[n] - m);
  red[t] = s; __syncthreads();
  for (int o = 64; o > 0; o >>= 1){
    if (t < o) red[t] += red[t + o];
    __syncthreads();
  }
  float inv = 1.f / (red[0] + 1e-8f);
  float4 sum = make_float4(0,0,0,0), wacc = make_float4(0,0,0,0);
  float4 mx = make_float4(-INFINITY,-INFINITY,-INFINITY,-INFINITY);
  for (int n = b; n < e; n++){
    float4 xv = load_hl(xH, xL, (size_t)n*DOUT + t*4);
    float p = expf(apre[n] - m) * inv;
    sum.x += xv.x; sum.y += xv.y; sum.z += xv.z; sum.w += xv.w;
    mx.x = fmaxf(mx.x, xv.x); mx.y = fmaxf(mx.y, xv.y);
    mx.z = fmaxf(mx.z, xv.z); mx.w = fmaxf(mx.w, xv.w);
    fma4(wacc, xv, p);
  }
  float ic = 1.f / fmaxf((float)(e - b), 1.f);
  float4* o = (float4*)(out + (size_t)g*4*DOUT);
  o[t]       = wacc;
  o[128 + t] = make_float4(sum.x*ic, sum.y*ic, sum.z*ic, sum.w*ic);
  o[256 + t] = mx;
  o[384 + t] = sum;
}

extern "C" void kernel_launch(void* const* d_in, const int* in_sizes, int n_in,
                              void* d_out, int out_size, void* d_ws, size_t ws_size,
                              hipStream_t stream) {
  const float* x0   = (const float*)d_in[0];
  const int*   ei   = (const int*)d_in[1];
  const int*   src  = ei;
  const int*   dst  = ei + NE;
  const int*   batch= (const int*)d_in[2];
  const float* gw[3]  = {(const float*)d_in[3],  (const float*)d_in[9],  (const float*)d_in[15]};
  const float* gb[3]  = {(const float*)d_in[4],  (const float*)d_in[10], (const float*)d_in[16]};
  const float* aw[3]  = {(const float*)d_in[5],  (const float*)d_in[11], (const float*)d_in[17]};
  const float* asw[3] = {(const float*)d_in[6],  (const float*)d_in[12], (const float*)d_in[18]};
  const float* adw[3] = {(const float*)d_in[7],  (const float*)d_in[13], (const float*)d_in[19]};
  const float* ab[3]  = {(const float*)d_in[8],  (const float*)d_in[14], (const float*)d_in[20]};
  const float* apw1 = (const float*)d_in[21];
  const float* apb1 = (const float*)d_in[22];
  const float* apw2 = (const float*)d_in[23];
  float* out = (float*)d_out;

  // ---- workspace carve ----
  char* p = (char*)d_ws;
  auto alloc = [&](size_t bytes) -> void* {
    void* r = (void*)p; p += (bytes + 255) & ~(size_t)255; return r;
  };
  float* f1 = (float*)alloc((size_t)NN*512*4);
  unsigned short* actH0 = (unsigned short*)alloc((size_t)NN*512*2);
  unsigned short* actL0 = (unsigned short*)alloc((size_t)NN*512*2);
  unsigned short* actH1 = (unsigned short*)alloc((size_t)NN*512*2);
  unsigned short* actL1 = (unsigned short*)alloc((size_t)NN*512*2);
  unsigned short* preH  = (unsigned short*)alloc((size_t)NN*256*2);
  unsigned short* preL  = (unsigned short*)alloc((size_t)NN*256*2);
  const int wK[7]  = {36, 128, 128, 256, 256, 512, 512};
  const int wM[7]  = {128, 128, 256, 256, 512, 512, 256};
  const int wKp[7] = {64, 128, 128, 256, 256, 512, 512};
  const float* wsrc[7] = {gw[0], aw[0], gw[1], aw[1], gw[2], aw[2], apw1};
  unsigned short* wTh[7]; unsigned short* wTl[7];
  for (int i = 0; i < 7; i++){
    size_t sz = (size_t)wM[i]*wKp[i]*2;
    wTh[i] = (unsigned short*)alloc(sz);
    wTl[i] = (unsigned short*)alloc(sz);
  }
  float* dinv = (float*)alloc(NN*4);
  float* as_  = (float*)alloc(NN*NH*4);
  float* ad_  = (float*)alloc(NN*NH*4);
  float* apre = (float*)alloc(NN*4);
  int* rowptr = (int*)alloc((NN+1)*4);
  int* colidx = (int*)alloc((size_t)NE*4);
  int* cnt    = (int*)alloc(NN*4);
  int* cursor = (int*)alloc(NN*4);
  int* starts = (int*)alloc((NB+1)*4);
  int* bsum   = (int*)alloc(SCAN_BLKS*4);

  // ---- conv descriptor (weights only) ----
  AllConv ac;
  int convTot = 0;
  for (int i = 0; i < 7; i++){
    ac.src[i] = wsrc[i]; ac.dh[i] = wTh[i]; ac.dl[i] = wTl[i];
    ac.K[i] = wK[i]; ac.Mm[i] = wM[i]; ac.Kp[i] = wKp[i];
    ac.tot[i] = wKp[i]*wM[i];
    convTot += ac.tot[i];
  }

  // ---- CSR build (count merged with conversions) -> scans -> fill ----
  hipMemsetAsync(cnt, 0, NN*sizeof(int), stream);
  int convBlks = (convTot + 255) / 256;
  k_count_conv<<<CNT_BLKS + convBlks, 256, 0, stream>>>(dst, cnt, ac, convTot);
  k_scan1<<<SCAN_BLKS, 256, 0, stream>>>(cnt, bsum, batch, starts);
  k_scan3<<<SCAN_BLKS, 256, 0, stream>>>(cnt, bsum, rowptr, dinv, cursor, apre);
  k_fill<<<(NE+255)/256, 256, 0, stream>>>(src, dst, rowptr, cursor, colidx);

  const int dims[4] = {36, 128, 256, 512};
  const int ngrp = (NN + 15) / 16;
  const unsigned short* curH = nullptr; const unsigned short* curL = nullptr;
  int wi = 0;
  for (int i = 0; i < 3; i++){
    int Kin = (i == 0) ? 64 : dims[i];
    int M = dims[i+1], C = M/NH;
    int nchunk_in = Kin / 64;
    int nchunk = M / 64;
    int nblk = (M/GBN) * ((NN+GBM-1)/GBM);
    if (i == 0){
      k_gcn_pre0<<<ngrp, 256, 0, stream>>>(x0, dinv, rowptr, colidx, preH, preL);
    } else {
      k_gcn_pre<<<nchunk_in*ngrp, 256, 0, stream>>>(curH, curL, dinv, rowptr, colidx,
                                                    preH, preL, Kin, nchunk_in);
    }
    k_gemm_bf3<<<nblk, 256, 0, stream>>>(preH, preL, wTh[wi], wTl[wi], f1, NN, wKp[wi], M,
                                         1, gb[i], actH0, actL0,
                                         nullptr, nullptr, nullptr, nullptr, C);
    wi++;
    k_gemm_bf3<<<nblk, 256, 0, stream>>>(actH0, actL0, wTh[wi], wTl[wi], f1, NN, wKp[wi], M,
                                         2, nullptr, nullptr, nullptr,
                                         asw[i], adw[i], as_, ad_, C);
    wi++;
    k_gat_gather<<<nchunk*ngrp, 256, 0, stream>>>(f1, actH0, actL0, rowptr, colidx,
                                                  as_, ad_, ab[i],
                                                  actH1, actL1, M, C, nchunk);
    curH = actH1; curL = actL1;
  }

  // ---- pooling ----
  {
    int nblk = (256/GBN) * ((NN+GBM-1)/GBM);
    k_gemm_bf3<<<nblk, 256, 0, stream>>>(actH1, actL1, wTh[6], wTl[6], f1, NN, wKp[6], 256,
                                         3, apb1, nullptr, nullptr,
                                         apw2, nullptr, apre, nullptr, 64);
  }
  k_pool<<<NB, 128, 0, stream>>>(actH1, actL1, apre, starts, out);
}